// Round 5
// baseline (759.766 us; speedup 1.0000x reference)
//
#include <hip/hip_runtime.h>
#include <hip/hip_bf16.h>

// Problem constants
#define N_ATOMS 262144
#define B_SZ    64
#define H_DIM   256
#define R_DIM   512

#define GEMM_BLOCKS    512
#define ROWS_PER_BLOCK (N_ATOMS / GEMM_BLOCKS)   // 512
#define SETS_PER_WAVE  (ROWS_PER_BLOCK / 128)    // 4  (8 waves x 16 rows)

typedef __attribute__((ext_vector_type(8))) short bf16x8;
typedef __attribute__((ext_vector_type(4))) float f32x4;

static __device__ __forceinline__ short f2bf(float f) {
  unsigned u = __builtin_bit_cast(unsigned, f);
  u = (u + 0x7FFFu + ((u >> 16) & 1u)) >> 16;   // RNE
  return (short)u;
}

static __device__ __forceinline__ bf16x8 pack8(f32x4 a0, f32x4 a1) {
  bf16x8 v;
  v[0] = f2bf(a0[0]); v[1] = f2bf(a0[1]); v[2] = f2bf(a0[2]); v[3] = f2bf(a0[3]);
  v[4] = f2bf(a1[0]); v[5] = f2bf(a1[1]); v[6] = f2bf(a1[2]); v[7] = f2bf(a1[3]);
  return v;
}

// ---------------------------------------------------------------------------
// Prep kernel: pooled only (B conversion moved into gemm).
//   pooled[b][o] = bl[o] + retj . Wl[o,256:512]
//   retj[j]      = bp[j] + meanr . Wp[j,:]
//   meanr[r]     = mean_k ret_feat[b][k][r]
// ---------------------------------------------------------------------------
__global__ __launch_bounds__(1024) void prep_kernel(
    const float* __restrict__ rf, const float* __restrict__ Wp,
    const float* __restrict__ bp, const float* __restrict__ Wl,
    const float* __restrict__ bl, float* __restrict__ pooled) {
  __shared__ float meanr[R_DIM];
  __shared__ float retj[H_DIM];
  int t    = threadIdx.x;
  int b    = blockIdx.x;
  int lane = t & 63;
  int w    = t >> 6;            // 16 waves

  if (t < R_DIM) {
    float s = 0.f;
    const float* p = rf + (long)b * 16 * R_DIM + t;
#pragma unroll
    for (int k = 0; k < 16; ++k) s += p[k * R_DIM];
    meanr[t] = s * (1.f / 16.f);
  }
  __syncthreads();

  {
    f32x4 m0 = *(const f32x4*)&meanr[lane * 8];
    f32x4 m1 = *(const f32x4*)&meanr[lane * 8 + 4];
#pragma unroll
    for (int jj = 0; jj < 16; ++jj) {
      int j = w * 16 + jj;
      const f32x4* wp = (const f32x4*)(Wp + (long)j * R_DIM + lane * 8);
      f32x4 w0 = wp[0], w1 = wp[1];
      float s = m0[0]*w0[0] + m0[1]*w0[1] + m0[2]*w0[2] + m0[3]*w0[3]
              + m1[0]*w1[0] + m1[1]*w1[1] + m1[2]*w1[2] + m1[3]*w1[3];
#pragma unroll
      for (int d = 1; d < 64; d <<= 1) s += __shfl_xor(s, d);
      if (lane == 0) retj[j] = s + bp[j];
    }
  }
  __syncthreads();

  {
    f32x4 r0 = *(const f32x4*)&retj[lane * 4];
#pragma unroll
    for (int oo = 0; oo < 16; ++oo) {
      int o = w * 16 + oo;
      f32x4 wv = *(const f32x4*)(Wl + (long)o * (2 * H_DIM) + H_DIM + lane * 4);
      float s = r0[0]*wv[0] + r0[1]*wv[1] + r0[2]*wv[2] + r0[3]*wv[3];
#pragma unroll
      for (int d = 1; d < 64; d <<= 1) s += __shfl_xor(s, d);
      if (lane == 0) pooled[b * H_DIM + o] = s + bl[o];
    }
  }
}

// ---------------------------------------------------------------------------
// GEMM: out[n][o] = sum_k h[n][k]*Wl[o][k] + pooled[batch[n]][o]
// B (256x256 bf16 = 128 KB) resident in LDS in MFMA fragment order, filled
// once per block from Wl (L2/L3-hot). Main loop: NO barriers, NO LDS writes,
// NO vmcnt(0). Each wave owns disjoint 16-row sets: A loaded from global in
// MFMA fragment layout (f32->bf16 in regs), next set prefetched during the
// current set's 128 MFMAs + 128 lane-linear ds_read_b128 (conflict-free).
// Bs layout: Bs[((ct*8+ks)*64+lane)*8 + j] = Wl[ct*16+(lane&15)][ks*32+(lane>>4)*8+j]
// ---------------------------------------------------------------------------
__global__ __launch_bounds__(512, 2) void gemm_kernel(
    const float* __restrict__ h, const float* __restrict__ Wl,
    const float* __restrict__ pooled, const int* __restrict__ batch,
    float* __restrict__ out) {
  __shared__ short Bs[16 * 8 * 64 * 8];   // 128 KiB
  int t    = threadIdx.x;
  int lane = t & 63;
  int w    = t >> 6;                       // 0..7

  // --- fill B into LDS (once), fragment order, lane-linear writes ---
#pragma unroll
  for (int i = 0; i < 16; ++i) {
    int idx8 = i * 512 + t;                // bf16x8 chunk index
    int l_   = idx8 & 63;
    int ks   = (idx8 >> 6) & 7;
    int ct   = idx8 >> 9;
    int o    = ct * 16 + (l_ & 15);
    int k    = ks * 32 + ((l_ >> 4) << 3);
    const f32x4* wp = (const f32x4*)(Wl + (long)o * (2 * H_DIM) + k);
    *(bf16x8*)&Bs[idx8 * 8] = pack8(wp[0], wp[1]);
  }
  __syncthreads();

  const int arow = lane & 15;
  const int kg   = lane >> 4;
  long rs = (long)blockIdx.x * ROWS_PER_BLOCK + w * 16;

  // --- prologue: load set 0 (16 rows, MFMA layout, f32) ---
  f32x4 av[8][2];
  {
    const float* ap = h + (rs + arow) * H_DIM + kg * 8;
#pragma unroll
    for (int ks = 0; ks < 8; ++ks) {
      av[ks][0] = *(const f32x4*)(ap + ks * 32);
      av[ks][1] = *(const f32x4*)(ap + ks * 32 + 4);
    }
  }

  for (int it = 0; it < SETS_PER_WAVE; ++it) {
    // convert current set to bf16 fragments
    bf16x8 af[8];
#pragma unroll
    for (int ks = 0; ks < 8; ++ks) af[ks] = pack8(av[ks][0], av[ks][1]);

    long rs_cur = rs;
    // issue next set's loads; they fly under the MFMA/ds_read section
    if (it + 1 < SETS_PER_WAVE) {
      rs += 128;
      const float* ap = h + (rs + arow) * H_DIM + kg * 8;
#pragma unroll
      for (int ks = 0; ks < 8; ++ks) {
        av[ks][0] = *(const f32x4*)(ap + ks * 32);
        av[ks][1] = *(const f32x4*)(ap + ks * 32 + 4);
      }
    }

    long rb = rs_cur + (kg << 2);
    int b0 = batch[rb + 0], b1 = batch[rb + 1];
    int b2 = batch[rb + 2], b3 = batch[rb + 3];
    const float* p0 = pooled + b0 * H_DIM;
    const float* p1 = pooled + b1 * H_DIM;
    const float* p2 = pooled + b2 * H_DIM;
    const float* p3 = pooled + b3 * H_DIM;

    // 16 col-tiles x 8 k-steps
    f32x4 acc[16];
#pragma unroll
    for (int ct = 0; ct < 16; ++ct) {
      f32x4 a_ = {0.f, 0.f, 0.f, 0.f};
#pragma unroll
      for (int ks = 0; ks < 8; ++ks) {
        bf16x8 bf = *(const bf16x8*)&Bs[(((ct * 8 + ks) << 6) + lane) << 3];
        a_ = __builtin_amdgcn_mfma_f32_16x16x32_bf16(af[ks], bf, a_, 0, 0, 0);
      }
      acc[ct] = a_;
    }

    // epilogue: pooled gather (L2-hot 64KB) + scattered dword stores
#pragma unroll
    for (int ct = 0; ct < 16; ++ct) {
      int o = ct * 16 + arow;
      float* ob = out + rb * H_DIM + o;
      ob[0 * H_DIM] = acc[ct][0] + p0[o];
      ob[1 * H_DIM] = acc[ct][1] + p1[o];
      ob[2 * H_DIM] = acc[ct][2] + p2[o];
      ob[3 * H_DIM] = acc[ct][3] + p3[o];
    }
  }
}

// ---------------------------------------------------------------------------
extern "C" void kernel_launch(void* const* d_in, const int* in_sizes, int n_in,
                              void* d_out, int out_size, void* d_ws, size_t ws_size,
                              hipStream_t stream) {
  const float* h   = (const float*)d_in[0];
  const float* rf  = (const float*)d_in[1];
  const int*   bat = (const int*)d_in[2];
  const float* Wp  = (const float*)d_in[3];
  const float* bp  = (const float*)d_in[4];
  const float* Wl  = (const float*)d_in[5];
  const float* bl  = (const float*)d_in[6];
  float* out = (float*)d_out;

  float* pooled = (float*)d_ws;                          // 64 KiB

  prep_kernel<<<B_SZ, 1024, 0, stream>>>(rf, Wp, bp, Wl, bl, pooled);
  gemm_kernel<<<GEMM_BLOCKS, 512, 0, stream>>>(h, Wl, pooled, bat, out);
}

// Round 7
// 351.621 us; speedup vs baseline: 2.1608x; 2.1608x over previous
//
#include <hip/hip_runtime.h>
#include <hip/hip_bf16.h>

// Problem constants
#define N_ATOMS 262144
#define B_SZ    64
#define H_DIM   256
#define R_DIM   512

#define GB       1024                 // gemm blocks
#define ROWS_PB  (N_ATOMS / GB)       // 256 rows per block
#define SETS     4                    // 16-row sets per wave (4 waves/block)

typedef __attribute__((ext_vector_type(8))) short bf16x8;
typedef __attribute__((ext_vector_type(4))) float f32x4;

static __device__ __forceinline__ short f2bf(float f) {
  unsigned u = __builtin_bit_cast(unsigned, f);
  u = (u + 0x7FFFu + ((u >> 16) & 1u)) >> 16;   // RNE
  return (short)u;
}

// v_cvt_pk_bf16_f32: packs 2 f32 -> 1 dword (2 bf16, RNE). No builtin on
// gfx950 (m240) — inline asm is the plain-HIP route.
static __device__ __forceinline__ unsigned cvtpk(float lo, float hi) {
  unsigned r;
  asm("v_cvt_pk_bf16_f32 %0, %1, %2" : "=v"(r) : "v"(lo), "v"(hi));
  return r;
}

static __device__ __forceinline__ bf16x8 pack8(f32x4 a0, f32x4 a1) {
  unsigned u0 = cvtpk(a0[0], a0[1]);
  unsigned u1 = cvtpk(a0[2], a0[3]);
  unsigned u2 = cvtpk(a1[0], a1[1]);
  unsigned u3 = cvtpk(a1[2], a1[3]);
  bf16x8 v;
  v[0] = (short)(u0 & 0xFFFF); v[1] = (short)(u0 >> 16);
  v[2] = (short)(u1 & 0xFFFF); v[3] = (short)(u1 >> 16);
  v[4] = (short)(u2 & 0xFFFF); v[5] = (short)(u2 >> 16);
  v[6] = (short)(u3 & 0xFFFF); v[7] = (short)(u3 >> 16);
  return v;
}

// ---------------------------------------------------------------------------
// Prep kernel (fused):
//   blocks [0,64):  pooled[b][o] = bl[o] + retj . Wl[o,256:512]
//   blocks [64,80): convert Wl[:, :256] to bf16 in MFMA fragment order:
//     Bbf[((ct*8+ks)*64+lane)*8+j] = Wl[ct*16+(lane&15)][ks*32+(lane>>4)*8+j]
// ---------------------------------------------------------------------------
__global__ __launch_bounds__(1024) void prep_kernel(
    const float* __restrict__ rf, const float* __restrict__ Wp,
    const float* __restrict__ bp, const float* __restrict__ Wl,
    const float* __restrict__ bl, float* __restrict__ pooled,
    short* __restrict__ Bbf) {
  int t = threadIdx.x;
  if (blockIdx.x >= B_SZ) {
    int base = (blockIdx.x - B_SZ) * 4096 + t * 4;
#pragma unroll
    for (int q = 0; q < 4; ++q) {
      int idx  = base + q;
      int j    = idx & 7;
      int lane = (idx >> 3) & 63;
      int ks   = (idx >> 9) & 7;
      int ct   = idx >> 12;
      int o    = ct * 16 + (lane & 15);
      int k    = ks * 32 + ((lane >> 4) << 3) + j;
      Bbf[idx] = f2bf(Wl[o * (2 * H_DIM) + k]);
    }
    return;
  }

  __shared__ float meanr[R_DIM];
  __shared__ float retj[H_DIM];
  int b    = blockIdx.x;
  int lane = t & 63;
  int w    = t >> 6;            // 16 waves

  if (t < R_DIM) {
    float s = 0.f;
    const float* p = rf + (long)b * 16 * R_DIM + t;
#pragma unroll
    for (int k = 0; k < 16; ++k) s += p[k * R_DIM];
    meanr[t] = s * (1.f / 16.f);
  }
  __syncthreads();

  {
    f32x4 m0 = *(const f32x4*)&meanr[lane * 8];
    f32x4 m1 = *(const f32x4*)&meanr[lane * 8 + 4];
#pragma unroll
    for (int jj = 0; jj < 16; ++jj) {
      int j = w * 16 + jj;
      const f32x4* wp = (const f32x4*)(Wp + (long)j * R_DIM + lane * 8);
      f32x4 w0 = wp[0], w1 = wp[1];
      float s = m0[0]*w0[0] + m0[1]*w0[1] + m0[2]*w0[2] + m0[3]*w0[3]
              + m1[0]*w1[0] + m1[1]*w1[1] + m1[2]*w1[2] + m1[3]*w1[3];
#pragma unroll
      for (int d = 1; d < 64; d <<= 1) s += __shfl_xor(s, d);
      if (lane == 0) retj[j] = s + bp[j];
    }
  }
  __syncthreads();

  {
    f32x4 r0 = *(const f32x4*)&retj[lane * 4];
#pragma unroll
    for (int oo = 0; oo < 16; ++oo) {
      int o = w * 16 + oo;
      f32x4 wv = *(const f32x4*)(Wl + (long)o * (2 * H_DIM) + H_DIM + lane * 4);
      float s = r0[0]*wv[0] + r0[1]*wv[1] + r0[2]*wv[2] + r0[3]*wv[3];
#pragma unroll
      for (int d = 1; d < 64; d <<= 1) s += __shfl_xor(s, d);
      if (lane == 0) pooled[b * H_DIM + o] = s + bl[o];
    }
  }
}

// ---------------------------------------------------------------------------
// GEMM: out[n][o] = sum_k h[n][k]*Wl[o][k] + pooled[batch[n]][o]
// No LDS, no barriers. 1024 blocks x 4 waves; wave owns 4 sets of 16 rows.
// Cross-set software pipeline: next set's A loads issued in two halves
// (at ctq0 and ctq2) so ~8 KB/wave of HBM reads stay in flight under the
// current set's 128 MFMAs. B-fragments stream from L2-hot Bbf (128 KB).
// SWAPPED MFMA (bfrag first): lane then holds 4 consecutive output cols
// (row = lane&15, cols = ct*16 + (lane>>4)*4 + 0..3) -> dwordx4 stores.
// ---------------------------------------------------------------------------
__global__ __launch_bounds__(256) void gemm_kernel(
    const float* __restrict__ h, const short* __restrict__ Bbf,
    const float* __restrict__ pooled, const int* __restrict__ batch,
    float* __restrict__ out) {
  int t    = threadIdx.x;
  int lane = t & 63;
  int w    = t >> 6;                       // 0..3
  const int arow = lane & 15;
  const int kg   = lane >> 4;              // 0..3
  long base = (long)blockIdx.x * ROWS_PB + w * 16;

  // --- prologue: load + convert set 0 ---
  bf16x8 af[8];
  {
    const float* ap = h + (base + arow) * H_DIM + kg * 8;
    f32x4 av[8][2];
#pragma unroll
    for (int ks = 0; ks < 8; ++ks) {
      av[ks][0] = *(const f32x4*)(ap + ks * 32);
      av[ks][1] = *(const f32x4*)(ap + ks * 32 + 4);
    }
#pragma unroll
    for (int ks = 0; ks < 8; ++ks) af[ks] = pack8(av[ks][0], av[ks][1]);
  }

  for (int s = 0; s < SETS; ++s) {
    long r0   = base + (long)s * 64;
    int  b    = batch[r0 + arow];
    const float* pb  = pooled + b * H_DIM;
    const float* apn = h + (r0 + 64 + arow) * H_DIM + kg * 8;
    bool more = (s + 1 < SETS);

    bf16x8 afn[8];
    f32x4  nv[4][2];

#pragma unroll
    for (int ctq = 0; ctq < 4; ++ctq) {
      if (ctq == 0 && more) {            // issue next-set loads, half 1
#pragma unroll
        for (int ks = 0; ks < 4; ++ks) {
          nv[ks][0] = *(const f32x4*)(apn + ks * 32);
          nv[ks][1] = *(const f32x4*)(apn + ks * 32 + 4);
        }
      }
      if (ctq == 2 && more) {            // convert half 1, issue half 2
#pragma unroll
        for (int ks = 0; ks < 4; ++ks) afn[ks] = pack8(nv[ks][0], nv[ks][1]);
#pragma unroll
        for (int ks = 0; ks < 4; ++ks) {
          nv[ks][0] = *(const f32x4*)(apn + (ks + 4) * 32);
          nv[ks][1] = *(const f32x4*)(apn + (ks + 4) * 32 + 4);
        }
      }
#pragma unroll
      for (int ci = 0; ci < 4; ++ci) {
        int ct = ctq * 4 + ci;
        const short* bb = Bbf + (((long)(ct * 8) * 64 + lane) << 3);
        f32x4 acc = {0.f, 0.f, 0.f, 0.f};
#pragma unroll
        for (int ks = 0; ks < 8; ++ks) {
          bf16x8 bf = *(const bf16x8*)(bb + ((long)ks << 9));
          acc = __builtin_amdgcn_mfma_f32_16x16x32_bf16(bf, af[ks], acc, 0, 0, 0);
        }
        int o0 = ct * 16 + (kg << 2);
        f32x4 pv = *(const f32x4*)(pb + o0);
        f32x4 res = acc + pv;
        *(f32x4*)(out + (r0 + arow) * H_DIM + o0) = res;
      }
    }

    if (more) {                          // convert half 2, rotate
#pragma unroll
      for (int ks = 0; ks < 4; ++ks) afn[ks + 4] = pack8(nv[ks][0], nv[ks][1]);
#pragma unroll
      for (int ks = 0; ks < 8; ++ks) af[ks] = afn[ks];
    }
  }
}

// ---------------------------------------------------------------------------
extern "C" void kernel_launch(void* const* d_in, const int* in_sizes, int n_in,
                              void* d_out, int out_size, void* d_ws, size_t ws_size,
                              hipStream_t stream) {
  const float* h   = (const float*)d_in[0];
  const float* rf  = (const float*)d_in[1];
  const int*   bat = (const int*)d_in[2];
  const float* Wp  = (const float*)d_in[3];
  const float* bp  = (const float*)d_in[4];
  const float* Wl  = (const float*)d_in[5];
  const float* bl  = (const float*)d_in[6];
  float* out = (float*)d_out;

  float* pooled = (float*)d_ws;                          // 64 KiB
  short* Bbf    = (short*)((char*)d_ws + 64 * 1024);     // 128 KiB

  prep_kernel<<<B_SZ + 16, 1024, 0, stream>>>(rf, Wp, bp, Wl, bl, pooled, Bbf);
  gemm_kernel<<<GB, 256, 0, stream>>>(h, Bbf, pooled, bat, out);
}

// Round 8
// 158.557 us; speedup vs baseline: 4.7917x; 2.2176x over previous
//
#include <hip/hip_runtime.h>
#include <hip/hip_bf16.h>

// Problem constants
#define N_ATOMS 262144
#define B_SZ    64
#define H_DIM   256
#define R_DIM   512

#define TILE_ROWS 64
#define NBLOCKS   (N_ATOMS / TILE_ROWS)   // 4096

typedef __attribute__((ext_vector_type(8))) short bf16x8;
typedef __attribute__((ext_vector_type(4))) float f32x4;

static __device__ __forceinline__ short f2bf(float f) {
  unsigned u = __builtin_bit_cast(unsigned, f);
  u = (u + 0x7FFFu + ((u >> 16) & 1u)) >> 16;   // RNE
  return (short)u;
}

// v_cvt_pk_bf16_f32: packs 2 f32 -> 1 dword (2 bf16, RNE). No builtin on
// gfx950 (m240) — inline asm is the plain-HIP route.
static __device__ __forceinline__ unsigned cvtpk(float lo, float hi) {
  unsigned r;
  asm("v_cvt_pk_bf16_f32 %0, %1, %2" : "=v"(r) : "v"(lo), "v"(hi));
  return r;
}

static __device__ __forceinline__ bf16x8 pack8(f32x4 a0, f32x4 a1) {
  unsigned u0 = cvtpk(a0[0], a0[1]);
  unsigned u1 = cvtpk(a0[2], a0[3]);
  unsigned u2 = cvtpk(a1[0], a1[1]);
  unsigned u3 = cvtpk(a1[2], a1[3]);
  bf16x8 v;
  v[0] = (short)(u0 & 0xFFFF); v[1] = (short)(u0 >> 16);
  v[2] = (short)(u1 & 0xFFFF); v[3] = (short)(u1 >> 16);
  v[4] = (short)(u2 & 0xFFFF); v[5] = (short)(u2 >> 16);
  v[6] = (short)(u3 & 0xFFFF); v[7] = (short)(u3 >> 16);
  return v;
}

// ---------------------------------------------------------------------------
// Prep kernel (fused):
//   blocks [0,64):  pooled[b][o] = bl[o] + retj . Wl[o,256:512]
//   blocks [64,80): convert Wl[:, :256] to bf16 in MFMA fragment order:
//     Bbf[((ct*8+ks)*64+lane)*8+j] = Wl[ct*16+(lane&15)][ks*32+(lane>>4)*8+j]
// ---------------------------------------------------------------------------
__global__ __launch_bounds__(1024) void prep_kernel(
    const float* __restrict__ rf, const float* __restrict__ Wp,
    const float* __restrict__ bp, const float* __restrict__ Wl,
    const float* __restrict__ bl, float* __restrict__ pooled,
    short* __restrict__ Bbf) {
  int t = threadIdx.x;
  if (blockIdx.x >= B_SZ) {
    int base = (blockIdx.x - B_SZ) * 4096 + t * 4;
#pragma unroll
    for (int q = 0; q < 4; ++q) {
      int idx  = base + q;
      int j    = idx & 7;
      int lane = (idx >> 3) & 63;
      int ks   = (idx >> 9) & 7;
      int ct   = idx >> 12;
      int o    = ct * 16 + (lane & 15);
      int k    = ks * 32 + ((lane >> 4) << 3) + j;
      Bbf[idx] = f2bf(Wl[o * (2 * H_DIM) + k]);
    }
    return;
  }

  __shared__ float meanr[R_DIM];
  __shared__ float retj[H_DIM];
  int b    = blockIdx.x;
  int lane = t & 63;
  int w    = t >> 6;            // 16 waves

  if (t < R_DIM) {
    float s = 0.f;
    const float* p = rf + (long)b * 16 * R_DIM + t;
#pragma unroll
    for (int k = 0; k < 16; ++k) s += p[k * R_DIM];
    meanr[t] = s * (1.f / 16.f);
  }
  __syncthreads();

  {
    f32x4 m0 = *(const f32x4*)&meanr[lane * 8];
    f32x4 m1 = *(const f32x4*)&meanr[lane * 8 + 4];
#pragma unroll
    for (int jj = 0; jj < 16; ++jj) {
      int j = w * 16 + jj;
      const f32x4* wp = (const f32x4*)(Wp + (long)j * R_DIM + lane * 8);
      f32x4 w0 = wp[0], w1 = wp[1];
      float s = m0[0]*w0[0] + m0[1]*w0[1] + m0[2]*w0[2] + m0[3]*w0[3]
              + m1[0]*w1[0] + m1[1]*w1[1] + m1[2]*w1[2] + m1[3]*w1[3];
#pragma unroll
      for (int d = 1; d < 64; d <<= 1) s += __shfl_xor(s, d);
      if (lane == 0) retj[j] = s + bp[j];
    }
  }
  __syncthreads();

  {
    f32x4 r0 = *(const f32x4*)&retj[lane * 4];
#pragma unroll
    for (int oo = 0; oo < 16; ++oo) {
      int o = w * 16 + oo;
      f32x4 wv = *(const f32x4*)(Wl + (long)o * (2 * H_DIM) + H_DIM + lane * 4);
      float s = r0[0]*wv[0] + r0[1]*wv[1] + r0[2]*wv[2] + r0[3]*wv[3];
#pragma unroll
      for (int d = 1; d < 64; d <<= 1) s += __shfl_xor(s, d);
      if (lane == 0) pooled[b * H_DIM + o] = s + bl[o];
    }
  }
}

// ---------------------------------------------------------------------------
// GEMM: out[n][o] = sum_k h[n][k]*Wl[o][k] + pooled[batch[n]][o]
// 4096 blocks x 512 threads (8 waves); block owns 64 rows x 256 cols,
// single-buffered, one barrier. Wave w owns col-tiles {2w, 2w+1}; both
// B-strips in registers (64 VGPR), loaded once from L2-hot Bbf.
// A staged in LDS in fragment-stripe order: stripe S = rt*8+ks holds the
// 16B MFMA A-fragment of each lane at As[(S*64+lane)*8] — ds_write_b128
// and ds_read_b128 are lane-linear => conflict-free by construction (r4: 0).
// SWAPPED MFMA (bfrag first): lane holds row = lane&15, cols = ct*16 +
// (lane>>4)*4 + 0..3 -> two adjacent dwordx4 stores per rt cover a full
// 128B line per row, issued back-to-back (no write amplification).
// ---------------------------------------------------------------------------
__global__ __launch_bounds__(512, 4) void gemm_kernel(
    const float* __restrict__ h, const short* __restrict__ Bbf,
    const float* __restrict__ pooled, const int* __restrict__ batch,
    float* __restrict__ out) {
  __shared__ short As[32 * 64 * 8];        // 32 KiB: 32 stripes x 64 lanes x 16B
  int t    = threadIdx.x;
  int lane = t & 63;
  int w    = t >> 6;                        // 0..7
  const int arow = lane & 15;
  const int kg   = lane >> 4;               // 0..3
  long m0 = (long)blockIdx.x * TILE_ROWS;

  // --- B strips for col-tiles 2w, 2w+1 (loaded once, 64 VGPR) ---
  bf16x8 bfrag0[8], bfrag1[8];
#pragma unroll
  for (int ks = 0; ks < 8; ++ks) {
    bfrag0[ks] = *(const bf16x8*)(Bbf + ((((2 * w)     * 8 + ks) * 64 + lane) << 3));
    bfrag1[ks] = *(const bf16x8*)(Bbf + ((((2 * w + 1) * 8 + ks) * 64 + lane) << 3));
  }

  // --- stage A: wave w stages stripes 4w..4w+3 ---
#pragma unroll
  for (int i = 0; i < 4; ++i) {
    int S   = 4 * w + i;
    int row = ((S >> 3) << 4) + arow;            // row within tile
    int kf  = ((S & 7) << 5) + (kg << 3);        // k offset in floats
    const float* p = h + (m0 + row) * H_DIM + kf;
    f32x4 a0 = *(const f32x4*)p;
    f32x4 a1 = *(const f32x4*)(p + 4);
    *(bf16x8*)&As[(S * 64 + lane) << 3] = pack8(a0, a1);
  }
  __syncthreads();

  // --- compute: 4 row-tiles x 2 col-tiles ---
  int o0 = ((2 * w) << 4) + (kg << 2);
  int o1 = o0 + 16;
#pragma unroll
  for (int rt = 0; rt < 4; ++rt) {
    f32x4 acc0 = {0.f, 0.f, 0.f, 0.f};
    f32x4 acc1 = {0.f, 0.f, 0.f, 0.f};
#pragma unroll
    for (int ks = 0; ks < 8; ++ks) {
      bf16x8 af = *(const bf16x8*)&As[((rt * 8 + ks) * 64 + lane) << 3];
      acc0 = __builtin_amdgcn_mfma_f32_16x16x32_bf16(bfrag0[ks], af, acc0, 0, 0, 0);
      acc1 = __builtin_amdgcn_mfma_f32_16x16x32_bf16(bfrag1[ks], af, acc1, 0, 0, 0);
    }
    long row = m0 + rt * 16 + arow;
    int  b   = batch[row];
    const float* pb = pooled + b * H_DIM;
    f32x4 pv0 = *(const f32x4*)(pb + o0);
    f32x4 pv1 = *(const f32x4*)(pb + o1);
    float* orow = out + row * H_DIM;
    *(f32x4*)(orow + o0) = acc0 + pv0;
    *(f32x4*)(orow + o1) = acc1 + pv1;
  }
}

// ---------------------------------------------------------------------------
extern "C" void kernel_launch(void* const* d_in, const int* in_sizes, int n_in,
                              void* d_out, int out_size, void* d_ws, size_t ws_size,
                              hipStream_t stream) {
  const float* h   = (const float*)d_in[0];
  const float* rf  = (const float*)d_in[1];
  const int*   bat = (const int*)d_in[2];
  const float* Wp  = (const float*)d_in[3];
  const float* bp  = (const float*)d_in[4];
  const float* Wl  = (const float*)d_in[5];
  const float* bl  = (const float*)d_in[6];
  float* out = (float*)d_out;

  float* pooled = (float*)d_ws;                          // 64 KiB
  short* Bbf    = (short*)((char*)d_ws + 64 * 1024);     // 128 KiB

  prep_kernel<<<B_SZ + 16, 1024, 0, stream>>>(rf, Wp, bp, Wl, bl, pooled, Bbf);
  gemm_kernel<<<NBLOCKS, 512, 0, stream>>>(h, Bbf, pooled, bat, out);
}

// Round 9
// 149.291 us; speedup vs baseline: 5.0892x; 1.0621x over previous
//
#include <hip/hip_runtime.h>
#include <hip/hip_bf16.h>

// Problem constants
#define N_ATOMS 262144
#define B_SZ    64
#define H_DIM   256
#define R_DIM   512

#define TILE_ROWS 32
#define TPB       16                        // tiles per block
#define NBLOCKS   (N_ATOMS / (TILE_ROWS * TPB))   // 512

typedef __attribute__((ext_vector_type(8))) short bf16x8;
typedef __attribute__((ext_vector_type(4))) float f32x4;

static __device__ __forceinline__ short f2bf(float f) {
  unsigned u = __builtin_bit_cast(unsigned, f);
  u = (u + 0x7FFFu + ((u >> 16) & 1u)) >> 16;   // RNE
  return (short)u;
}

// v_cvt_pk_bf16_f32: packs 2 f32 -> 1 dword (2 bf16, RNE). No builtin on
// gfx950 (m240) — inline asm is the plain-HIP route.
static __device__ __forceinline__ unsigned cvtpk(float lo, float hi) {
  unsigned r;
  asm("v_cvt_pk_bf16_f32 %0, %1, %2" : "=v"(r) : "v"(lo), "v"(hi));
  return r;
}

static __device__ __forceinline__ bf16x8 pack8(f32x4 a0, f32x4 a1) {
  unsigned u0 = cvtpk(a0[0], a0[1]);
  unsigned u1 = cvtpk(a0[2], a0[3]);
  unsigned u2 = cvtpk(a1[0], a1[1]);
  unsigned u3 = cvtpk(a1[2], a1[3]);
  bf16x8 v;
  v[0] = (short)(u0 & 0xFFFF); v[1] = (short)(u0 >> 16);
  v[2] = (short)(u1 & 0xFFFF); v[3] = (short)(u1 >> 16);
  v[4] = (short)(u2 & 0xFFFF); v[5] = (short)(u2 >> 16);
  v[6] = (short)(u3 & 0xFFFF); v[7] = (short)(u3 >> 16);
  return v;
}

// async global->LDS DMA, 16B per lane; LDS dest = wave-uniform base + lane*16
static __device__ __forceinline__ void async_copy16(const float* g, short* lds) {
  __builtin_amdgcn_global_load_lds(
      (const __attribute__((address_space(1))) unsigned int*)g,
      (__attribute__((address_space(3))) unsigned int*)lds,
      16, 0, 0);
}

// ---------------------------------------------------------------------------
// Prep kernel (fused):
//   blocks [0,64):  pooled[b][o] = bl[o] + retj . Wl[o,256:512]
//   blocks [64,80): convert Wl[:, :256] to bf16 in MFMA fragment order:
//     Bbf[((ct*8+ks)*64+lane)*8+j] = Wl[ct*16+(lane&15)][ks*32+(lane>>4)*8+j]
// ---------------------------------------------------------------------------
__global__ __launch_bounds__(1024) void prep_kernel(
    const float* __restrict__ rf, const float* __restrict__ Wp,
    const float* __restrict__ bp, const float* __restrict__ Wl,
    const float* __restrict__ bl, float* __restrict__ pooled,
    short* __restrict__ Bbf) {
  int t = threadIdx.x;
  if (blockIdx.x >= B_SZ) {
    int base = (blockIdx.x - B_SZ) * 4096 + t * 4;
#pragma unroll
    for (int q = 0; q < 4; ++q) {
      int idx  = base + q;
      int j    = idx & 7;
      int lane = (idx >> 3) & 63;
      int ks   = (idx >> 9) & 7;
      int ct   = idx >> 12;
      int o    = ct * 16 + (lane & 15);
      int k    = ks * 32 + ((lane >> 4) << 3) + j;
      Bbf[idx] = f2bf(Wl[o * (2 * H_DIM) + k]);
    }
    return;
  }

  __shared__ float meanr[R_DIM];
  __shared__ float retj[H_DIM];
  int b    = blockIdx.x;
  int lane = t & 63;
  int w    = t >> 6;            // 16 waves

  if (t < R_DIM) {
    float s = 0.f;
    const float* p = rf + (long)b * 16 * R_DIM + t;
#pragma unroll
    for (int k = 0; k < 16; ++k) s += p[k * R_DIM];
    meanr[t] = s * (1.f / 16.f);
  }
  __syncthreads();

  {
    f32x4 m0 = *(const f32x4*)&meanr[lane * 8];
    f32x4 m1 = *(const f32x4*)&meanr[lane * 8 + 4];
#pragma unroll
    for (int jj = 0; jj < 16; ++jj) {
      int j = w * 16 + jj;
      const f32x4* wp = (const f32x4*)(Wp + (long)j * R_DIM + lane * 8);
      f32x4 w0 = wp[0], w1 = wp[1];
      float s = m0[0]*w0[0] + m0[1]*w0[1] + m0[2]*w0[2] + m0[3]*w0[3]
              + m1[0]*w1[0] + m1[1]*w1[1] + m1[2]*w1[2] + m1[3]*w1[3];
#pragma unroll
      for (int d = 1; d < 64; d <<= 1) s += __shfl_xor(s, d);
      if (lane == 0) retj[j] = s + bp[j];
    }
  }
  __syncthreads();

  {
    f32x4 r0 = *(const f32x4*)&retj[lane * 4];
#pragma unroll
    for (int oo = 0; oo < 16; ++oo) {
      int o = w * 16 + oo;
      f32x4 wv = *(const f32x4*)(Wl + (long)o * (2 * H_DIM) + H_DIM + lane * 4);
      float s = r0[0]*wv[0] + r0[1]*wv[1] + r0[2]*wv[2] + r0[3]*wv[3];
#pragma unroll
      for (int d = 1; d < 64; d <<= 1) s += __shfl_xor(s, d);
      if (lane == 0) pooled[b * H_DIM + o] = s + bl[o];
    }
  }
}

// ---------------------------------------------------------------------------
// GEMM: out[n][o] = sum_k h[n][k]*Wl[o][k] + pooled[batch[n]][o]
// 512 persistent blocks x 512 threads (8 waves), 16 tiles of 32 rows each,
// double-buffered LDS (2 x 32 KiB raw f32 A-tiles).
// Per tile: STAGE(next via global_load_lds) -> compute(cur) -> syncthreads.
// LDS stripe S = rt*16 + ks*2 + hk (1 KiB each): lane's 16B at S*1024+lane*16
// holds h[g0 + (S>>4)*16 + (lane&15)][((S>>1)&7)*32 + (lane>>4)*8 + (S&1)*4 ..+3]
// => DMA dest is wave-uniform base + lane*16 (HW pattern), ds_read_b128 is
// lane-linear (conflict-free, r4/r8: 0 conflicts). f32->bf16 at read time.
// Wave w owns col-tiles {2w, 2w+1}: B strips in registers (64 VGPR).
// SWAPPED MFMA (bfrag first): lane holds row=lane&15, cols=ct*16+(lane>>4)*4
// -> two adjacent dwordx4 stores per rt (full 128B lines, r8-verified).
// ---------------------------------------------------------------------------
__global__ __launch_bounds__(512, 4) void gemm_kernel(
    const float* __restrict__ h, const short* __restrict__ Bbf,
    const float* __restrict__ pooled, const int* __restrict__ batch,
    float* __restrict__ out) {
  __shared__ short As[2][32 * 512];        // 2 x 32 KiB (raw f32 stripes)
  int t    = threadIdx.x;
  int lane = t & 63;
  int w    = t >> 6;                        // 0..7
  const int arow = lane & 15;
  const int kg   = lane >> 4;               // 0..3

  // --- B strips for col-tiles 2w, 2w+1 (loaded once, 64 VGPR) ---
  bf16x8 bfrag0[8], bfrag1[8];
#pragma unroll
  for (int ks = 0; ks < 8; ++ks) {
    bfrag0[ks] = *(const bf16x8*)(Bbf + ((((2 * w)     * 8 + ks) * 64 + lane) << 3));
    bfrag1[ks] = *(const bf16x8*)(Bbf + ((((2 * w + 1) * 8 + ks) * 64 + lane) << 3));
  }

  // stage geometry: wave w DMAs stripes 4w..4w+3 of a tile
  int S_[4], row_[4], col_[4];
#pragma unroll
  for (int i = 0; i < 4; ++i) {
    int S   = 4 * w + i;
    S_[i]   = S;
    row_[i] = ((S >> 4) << 4) + arow;
    col_[i] = (((S >> 1) & 7) << 5) + (kg << 3) + ((S & 1) << 2);
  }

  long base_row = (long)blockIdx.x * (TILE_ROWS * TPB);

  // --- prologue: stage tile 0 into buf 0 ---
#pragma unroll
  for (int i = 0; i < 4; ++i)
    async_copy16(h + (base_row + row_[i]) * H_DIM + col_[i],
                 &As[0][S_[i] * 512]);
  __syncthreads();

  int o0 = ((2 * w) << 4) + (kg << 2);
  int o1 = o0 + 16;

  for (int tt = 0; tt < TPB; ++tt) {
    int  buf = tt & 1;
    long g0  = base_row + (long)tt * TILE_ROWS;

    // --- stage next tile into other buffer (in flight during compute) ---
    if (tt + 1 < TPB) {
      long gn = g0 + TILE_ROWS;
#pragma unroll
      for (int i = 0; i < 4; ++i)
        async_copy16(h + (gn + row_[i]) * H_DIM + col_[i],
                     &As[buf ^ 1][S_[i] * 512]);
    }

    // --- compute 2 row-tiles x 2 col-tiles from buf ---
#pragma unroll
    for (int rt = 0; rt < 2; ++rt) {
      f32x4 acc0 = {0.f, 0.f, 0.f, 0.f};
      f32x4 acc1 = {0.f, 0.f, 0.f, 0.f};
#pragma unroll
      for (int ks = 0; ks < 8; ++ks) {
        int S0 = rt * 16 + ks * 2;
        f32x4 v0 = *(const f32x4*)&As[buf][(S0 * 512) + lane * 8];
        f32x4 v1 = *(const f32x4*)&As[buf][((S0 + 1) * 512) + lane * 8];
        bf16x8 af = pack8(v0, v1);
        acc0 = __builtin_amdgcn_mfma_f32_16x16x32_bf16(bfrag0[ks], af, acc0, 0, 0, 0);
        acc1 = __builtin_amdgcn_mfma_f32_16x16x32_bf16(bfrag1[ks], af, acc1, 0, 0, 0);
      }
      long row = g0 + rt * 16 + arow;
      int  b   = batch[row];
      const float* pb = pooled + b * H_DIM;
      f32x4 pv0 = *(const f32x4*)(pb + o0);
      f32x4 pv1 = *(const f32x4*)(pb + o1);
      float* orow = out + row * H_DIM;
      *(f32x4*)(orow + o0) = acc0 + pv0;
      *(f32x4*)(orow + o1) = acc1 + pv1;
    }

    __syncthreads();   // drains DMA for next tile; guards buf reuse
  }
}

// ---------------------------------------------------------------------------
extern "C" void kernel_launch(void* const* d_in, const int* in_sizes, int n_in,
                              void* d_out, int out_size, void* d_ws, size_t ws_size,
                              hipStream_t stream) {
  const float* h   = (const float*)d_in[0];
  const float* rf  = (const float*)d_in[1];
  const int*   bat = (const int*)d_in[2];
  const float* Wp  = (const float*)d_in[3];
  const float* bp  = (const float*)d_in[4];
  const float* Wl  = (const float*)d_in[5];
  const float* bl  = (const float*)d_in[6];
  float* out = (float*)d_out;

  float* pooled = (float*)d_ws;                          // 64 KiB
  short* Bbf    = (short*)((char*)d_ws + 64 * 1024);     // 128 KiB

  prep_kernel<<<B_SZ + 16, 1024, 0, stream>>>(rf, Wp, bp, Wl, bl, pooled, Bbf);
  gemm_kernel<<<NBLOCKS, 512, 0, stream>>>(h, Bbf, pooled, bat, out);
}

// Round 10
// 144.012 us; speedup vs baseline: 5.2757x; 1.0367x over previous
//
#include <hip/hip_runtime.h>
#include <hip/hip_bf16.h>

// Problem constants
#define N_ATOMS 262144
#define B_SZ    64
#define H_DIM   256
#define R_DIM   512

#define TILE_ROWS 32
#define TPB       16                        // tiles per block
#define NBLOCKS   (N_ATOMS / (TILE_ROWS * TPB))   // 512

typedef __attribute__((ext_vector_type(8))) short bf16x8;
typedef __attribute__((ext_vector_type(4))) float f32x4;

static __device__ __forceinline__ short f2bf(float f) {
  unsigned u = __builtin_bit_cast(unsigned, f);
  u = (u + 0x7FFFu + ((u >> 16) & 1u)) >> 16;   // RNE
  return (short)u;
}

// v_cvt_pk_bf16_f32: packs 2 f32 -> 1 dword (2 bf16, RNE). No builtin on
// gfx950 (m240) — inline asm is the plain-HIP route.
static __device__ __forceinline__ unsigned cvtpk(float lo, float hi) {
  unsigned r;
  asm("v_cvt_pk_bf16_f32 %0, %1, %2" : "=v"(r) : "v"(lo), "v"(hi));
  return r;
}

static __device__ __forceinline__ bf16x8 pack8(f32x4 a0, f32x4 a1) {
  unsigned u0 = cvtpk(a0[0], a0[1]);
  unsigned u1 = cvtpk(a0[2], a0[3]);
  unsigned u2 = cvtpk(a1[0], a1[1]);
  unsigned u3 = cvtpk(a1[2], a1[3]);
  bf16x8 v;
  v[0] = (short)(u0 & 0xFFFF); v[1] = (short)(u0 >> 16);
  v[2] = (short)(u1 & 0xFFFF); v[3] = (short)(u1 >> 16);
  v[4] = (short)(u2 & 0xFFFF); v[5] = (short)(u2 >> 16);
  v[6] = (short)(u3 & 0xFFFF); v[7] = (short)(u3 >> 16);
  return v;
}

// async global->LDS DMA, 16B per lane; LDS dest = wave-uniform base + lane*16
static __device__ __forceinline__ void async_copy16(const float* g, short* lds) {
  __builtin_amdgcn_global_load_lds(
      (const __attribute__((address_space(1))) unsigned int*)g,
      (__attribute__((address_space(3))) unsigned int*)lds,
      16, 0, 0);
}

// ---------------------------------------------------------------------------
// Prep kernel (fused):
//   blocks [0,64):  pooled[b][o] = bl[o] + retj . Wl[o,256:512]
//   blocks [64,80): convert Wl[:, :256] to bf16 in MFMA fragment order:
//     Bbf[((ct*8+ks)*64+lane)*8+j] = Wl[ct*16+(lane&15)][ks*32+(lane>>4)*8+j]
// ---------------------------------------------------------------------------
__global__ __launch_bounds__(1024) void prep_kernel(
    const float* __restrict__ rf, const float* __restrict__ Wp,
    const float* __restrict__ bp, const float* __restrict__ Wl,
    const float* __restrict__ bl, float* __restrict__ pooled,
    short* __restrict__ Bbf) {
  int t = threadIdx.x;
  if (blockIdx.x >= B_SZ) {
    int base = (blockIdx.x - B_SZ) * 4096 + t * 4;
#pragma unroll
    for (int q = 0; q < 4; ++q) {
      int idx  = base + q;
      int j    = idx & 7;
      int lane = (idx >> 3) & 63;
      int ks   = (idx >> 9) & 7;
      int ct   = idx >> 12;
      int o    = ct * 16 + (lane & 15);
      int k    = ks * 32 + ((lane >> 4) << 3) + j;
      Bbf[idx] = f2bf(Wl[o * (2 * H_DIM) + k]);
    }
    return;
  }

  __shared__ float meanr[R_DIM];
  __shared__ float retj[H_DIM];
  int b    = blockIdx.x;
  int lane = t & 63;
  int w    = t >> 6;            // 16 waves

  if (t < R_DIM) {
    float s = 0.f;
    const float* p = rf + (long)b * 16 * R_DIM + t;
#pragma unroll
    for (int k = 0; k < 16; ++k) s += p[k * R_DIM];
    meanr[t] = s * (1.f / 16.f);
  }
  __syncthreads();

  {
    f32x4 m0 = *(const f32x4*)&meanr[lane * 8];
    f32x4 m1 = *(const f32x4*)&meanr[lane * 8 + 4];
#pragma unroll
    for (int jj = 0; jj < 16; ++jj) {
      int j = w * 16 + jj;
      const f32x4* wp = (const f32x4*)(Wp + (long)j * R_DIM + lane * 8);
      f32x4 w0 = wp[0], w1 = wp[1];
      float s = m0[0]*w0[0] + m0[1]*w0[1] + m0[2]*w0[2] + m0[3]*w0[3]
              + m1[0]*w1[0] + m1[1]*w1[1] + m1[2]*w1[2] + m1[3]*w1[3];
#pragma unroll
      for (int d = 1; d < 64; d <<= 1) s += __shfl_xor(s, d);
      if (lane == 0) retj[j] = s + bp[j];
    }
  }
  __syncthreads();

  {
    f32x4 r0 = *(const f32x4*)&retj[lane * 4];
#pragma unroll
    for (int oo = 0; oo < 16; ++oo) {
      int o = w * 16 + oo;
      f32x4 wv = *(const f32x4*)(Wl + (long)o * (2 * H_DIM) + H_DIM + lane * 4);
      float s = r0[0]*wv[0] + r0[1]*wv[1] + r0[2]*wv[2] + r0[3]*wv[3];
#pragma unroll
      for (int d = 1; d < 64; d <<= 1) s += __shfl_xor(s, d);
      if (lane == 0) pooled[b * H_DIM + o] = s + bl[o];
    }
  }
}

// ---------------------------------------------------------------------------
// GEMM: out[n][o] = sum_k h[n][k]*Wl[o][k] + pooled[batch[n]][o]
// 512 persistent blocks x 512 threads (8 waves), 16 tiles of 32 rows,
// double-buffered LDS (2 x 32 KiB raw f32 A-tiles) via global_load_lds.
//
// KEY ORDERING (vmcnt retires IN ORDER): per tile, ALL epilogue VMEM loads
// (batch + pooled) are issued BEFORE the next-tile DMAs, pinned by
// sched_barrier(0). Any VMEM load issued after the DMAs would force the
// compiler's wait-before-use to drain the DMAs mid-compute, serializing the
// pipeline (this was round 9's hidden stall). After the hoist, the only ops
// younger than the DMAs are stores, which nothing waits on until the barrier.
//
// LDS stripe S (1 KiB): lane's 16B at S*1024+lane*16 holds
// h[g0+(S>>4)*16+(lane&15)][((S>>1)&7)*32+(lane>>4)*8+(S&1)*4 ..+3]
// => DMA dest wave-uniform base + lane*16; ds_read_b128 lane-linear (0 conf).
// Wave w owns col-tiles {2w,2w+1}: B strips in registers.
// SWAPPED MFMA (bfrag first): row=lane&15, cols=ct*16+(lane>>4)*4 ->
// two adjacent nontemporal dwordx4 stores per rt (full 128B lines).
// ---------------------------------------------------------------------------
__global__ __launch_bounds__(512, 4) void gemm_kernel(
    const float* __restrict__ h, const short* __restrict__ Bbf,
    const float* __restrict__ pooled, const int* __restrict__ batch,
    float* __restrict__ out) {
  __shared__ short As[2][32 * 512];        // 2 x 32 KiB (raw f32 stripes)
  int t    = threadIdx.x;
  int lane = t & 63;
  int w    = t >> 6;                        // 0..7
  const int arow = lane & 15;
  const int kg   = lane >> 4;               // 0..3

  // --- B strips for col-tiles 2w, 2w+1 (loaded once, 64 VGPR) ---
  bf16x8 bfrag0[8], bfrag1[8];
#pragma unroll
  for (int ks = 0; ks < 8; ++ks) {
    bfrag0[ks] = *(const bf16x8*)(Bbf + ((((2 * w)     * 8 + ks) * 64 + lane) << 3));
    bfrag1[ks] = *(const bf16x8*)(Bbf + ((((2 * w + 1) * 8 + ks) * 64 + lane) << 3));
  }

  // stage geometry: wave w DMAs stripes 4w..4w+3 of a tile
  int S_[4], row_[4], col_[4];
#pragma unroll
  for (int i = 0; i < 4; ++i) {
    int S   = 4 * w + i;
    S_[i]   = S;
    row_[i] = ((S >> 4) << 4) + arow;
    col_[i] = (((S >> 1) & 7) << 5) + (kg << 3) + ((S & 1) << 2);
  }

  long base_row = (long)blockIdx.x * (TILE_ROWS * TPB);

  // --- prologue: stage tile 0 into buf 0 ---
#pragma unroll
  for (int i = 0; i < 4; ++i)
    async_copy16(h + (base_row + row_[i]) * H_DIM + col_[i],
                 &As[0][S_[i] * 512]);
  __syncthreads();

  int o0 = ((2 * w) << 4) + (kg << 2);
  int o1 = o0 + 16;

  for (int tt = 0; tt < TPB; ++tt) {
    int  buf = tt & 1;
    long g0  = base_row + (long)tt * TILE_ROWS;

    // --- (1) epilogue VMEM loads for CURRENT tile, BEFORE any DMA issue ---
    long row0 = g0 + arow;
    long row1 = g0 + 16 + arow;
    int  b0 = batch[row0];
    int  b1 = batch[row1];
    const float* pb0 = pooled + b0 * H_DIM;
    const float* pb1 = pooled + b1 * H_DIM;
    f32x4 pv00 = *(const f32x4*)(pb0 + o0);
    f32x4 pv01 = *(const f32x4*)(pb0 + o1);
    f32x4 pv10 = *(const f32x4*)(pb1 + o0);
    f32x4 pv11 = *(const f32x4*)(pb1 + o1);
    __builtin_amdgcn_sched_barrier(0);   // pin: loads above, DMAs below

    // --- (2) stage next tile into other buffer (flies across compute) ---
    if (tt + 1 < TPB) {
      long gn = g0 + TILE_ROWS;
#pragma unroll
      for (int i = 0; i < 4; ++i)
        async_copy16(h + (gn + row_[i]) * H_DIM + col_[i],
                     &As[buf ^ 1][S_[i] * 512]);
    }

    // --- (3) compute 2 row-tiles x 2 col-tiles from buf (LDS + regs only) ---
#pragma unroll
    for (int rt = 0; rt < 2; ++rt) {
      f32x4 acc0 = {0.f, 0.f, 0.f, 0.f};
      f32x4 acc1 = {0.f, 0.f, 0.f, 0.f};
#pragma unroll
      for (int ks = 0; ks < 8; ++ks) {
        int S0 = rt * 16 + ks * 2;
        f32x4 v0 = *(const f32x4*)&As[buf][(S0 * 512) + lane * 8];
        f32x4 v1 = *(const f32x4*)&As[buf][((S0 + 1) * 512) + lane * 8];
        bf16x8 af = pack8(v0, v1);
        acc0 = __builtin_amdgcn_mfma_f32_16x16x32_bf16(bfrag0[ks], af, acc0, 0, 0, 0);
        acc1 = __builtin_amdgcn_mfma_f32_16x16x32_bf16(bfrag1[ks], af, acc1, 0, 0, 0);
      }
      long row = (rt == 0) ? row0 : row1;
      f32x4 r0v = acc0 + ((rt == 0) ? pv00 : pv10);
      f32x4 r1v = acc1 + ((rt == 0) ? pv01 : pv11);
      float* orow = out + row * H_DIM;
      __builtin_nontemporal_store(r0v, (f32x4*)(orow + o0));
      __builtin_nontemporal_store(r1v, (f32x4*)(orow + o1));
    }

    __syncthreads();   // drains DMA (already retired at BW rate) + stores
  }
}

// ---------------------------------------------------------------------------
extern "C" void kernel_launch(void* const* d_in, const int* in_sizes, int n_in,
                              void* d_out, int out_size, void* d_ws, size_t ws_size,
                              hipStream_t stream) {
  const float* h   = (const float*)d_in[0];
  const float* rf  = (const float*)d_in[1];
  const int*   bat = (const int*)d_in[2];
  const float* Wp  = (const float*)d_in[3];
  const float* bp  = (const float*)d_in[4];
  const float* Wl  = (const float*)d_in[5];
  const float* bl  = (const float*)d_in[6];
  float* out = (float*)d_out;

  float* pooled = (float*)d_ws;                          // 64 KiB
  short* Bbf    = (short*)((char*)d_ws + 64 * 1024);     // 128 KiB

  prep_kernel<<<B_SZ + 16, 1024, 0, stream>>>(rf, Wp, bp, Wl, bl, pooled, Bbf);
  gemm_kernel<<<NBLOCKS, 512, 0, stream>>>(h, Bbf, pooled, bat, out);
}